// Round 4
// baseline (253.188 us; speedup 1.0000x reference)
//
#include <hip/hip_runtime.h>

#define BB 8
#define TT 4096
#define DD 1024
#define KK 64
#define DT 256        // channels per K1 block (1 thread = 1 channel)
#define L1SEG 256     // output rows per K1 block
#define TC 16         // t-rows per K2 block

// Kernel 1: register-resident sliding-window f64 recurrence -> packed spike bits.
// No LDS, no barriers. Thread owns channel d. History x[t-64..t-1] lives in 64
// f32 registers (va/vb alternate roles per 64-row phase; all indices static via
// full unroll). Each phase issues 64 independent coalesced loads (16 KB/wave in
// flight) then consumes in order -> compiler emits counted vmcnt, no drains.
__global__ __launch_bounds__(256) void lif_spike_kernel(
    const float* __restrict__ x, const float* __restrict__ threshold,
    const float* __restrict__ tau, const float* __restrict__ v0p,
    unsigned long long* __restrict__ masks)
{
    const int tid   = threadIdx.x;
    const int tseg  = blockIdx.x;
    const int dtile = blockIdx.y;
    const int b     = blockIdx.z;
    const int d     = dtile * DT + tid;
    const int t0    = tseg * L1SEG;

    double tc = (double)tau[d];
    tc = tc < 0.001 ? 0.001 : (tc > 0.999 ? 0.999 : tc);
    const double ltau = log(tc);
    const double c64  = exp(64.0 * ltau);   // tau^64
    const double thr  = (double)threshold[d];
    const double v0   = (double)v0p[d];
    double pw  = exp((double)(t0 + 1) * ltau);
    double acc = 0.0;

    const float* xcol = x + ((size_t)b * TT) * DD + d;   // column d, stride DD
    const int lane = tid & 63;
    const int wg   = dtile * 4 + (tid >> 6);
    unsigned long long* mrow = masks + ((size_t)b * TT) * 16 + wg;

    float va[KK], vb[KK];

    // Warm-up: rows t0-64 .. t0-1 -> va, build running window sum.
    {
        const int tb = t0 - KK;
        if (tb >= 0) {                      // uniform branch; unguarded fast path
            #pragma unroll
            for (int i = 0; i < KK; ++i) va[i] = xcol[(size_t)(tb + i) * DD];
        } else {                            // only tseg==0
            #pragma unroll
            for (int i = 0; i < KK; ++i)
                va[i] = (tb + i >= 0) ? xcol[(size_t)(tb + i) * DD] : 0.0f;
        }
        #pragma unroll
        for (int i = 0; i < KK; ++i) acc = fma(tc, acc, (double)va[i]);
    }

    // Main: L1SEG/128 iterations of an A/B phase pair (64 rows each).
    for (int s = 0; s < L1SEG / (2 * KK); ++s) {
        const int tbA = t0 + s * 2 * KK;

        // Phase A: new rows -> vb, old (t-64) in va
        #pragma unroll
        for (int i = 0; i < KK; ++i) vb[i] = xcol[(size_t)(tbA + i) * DD];
        #pragma unroll
        for (int i = 0; i < KK; ++i) {
            acc = fma(tc, acc, (double)vb[i]);       // + x[t]
            acc = fma(-c64, (double)va[i], acc);     // - tau^64 * x[t-64]
            const double vint = fma(v0, pw, acc);
            pw *= tc;
            const unsigned long long m = __ballot(vint >= thr);
            if (lane == 0) mrow[(size_t)(tbA + i) * 16] = m;
        }

        // Phase B: new rows -> va, old (t-64) in vb
        const int tbB = tbA + KK;
        #pragma unroll
        for (int i = 0; i < KK; ++i) va[i] = xcol[(size_t)(tbB + i) * DD];
        #pragma unroll
        for (int i = 0; i < KK; ++i) {
            acc = fma(tc, acc, (double)va[i]);
            acc = fma(-c64, (double)vb[i], acc);
            const double vint = fma(v0, pw, acc);
            pw *= tc;
            const unsigned long long m = __ballot(vint >= thr);
            if (lane == 0) mrow[(size_t)(tbB + i) * 16] = m;
        }
    }
}

// Kernel 2: popcount -> denom -> normalized float4 output (unchanged control)
__global__ __launch_bounds__(256) void lif_norm_kernel(
    const unsigned long long* __restrict__ masks,
    float* __restrict__ out)
{
    __shared__ unsigned long long mw[TC * 16];
    __shared__ float rcp[TC];
    const int tid    = threadIdx.x;
    const int tchunk = blockIdx.x;
    const int b      = blockIdx.y;
    const int tbase  = tchunk * TC;

    mw[tid] = masks[((size_t)b * TT + tbase) * 16 + tid];
    __syncthreads();

    if (tid < TC) {
        int cnt = 0;
        #pragma unroll
        for (int w = 0; w < 16; ++w) cnt += __popcll(mw[tid * 16 + w]);
        rcp[tid] = 1.0f / fmaxf((float)cnt, 1.0f);
    }
    __syncthreads();

    float4* outb = (float4*)(out + ((size_t)b * TT + tbase) * DD) + tid;
    #pragma unroll
    for (int t = 0; t < TC; ++t) {
        const unsigned long long w = mw[t * 16 + (tid >> 4)];
        const unsigned int bits = (unsigned int)(w >> ((tid & 15) * 4)) & 0xFu;
        const float r = rcp[t];
        float4 o;
        o.x = (bits & 1u) ? r : 0.0f;
        o.y = (bits & 2u) ? r : 0.0f;
        o.z = (bits & 4u) ? r : 0.0f;
        o.w = (bits & 8u) ? r : 0.0f;
        outb[t * (DD / 4)] = o;
    }
}

extern "C" void kernel_launch(void* const* d_in, const int* in_sizes, int n_in,
                              void* d_out, int out_size, void* d_ws, size_t ws_size,
                              hipStream_t stream) {
    const float* x         = (const float*)d_in[0];
    const float* threshold = (const float*)d_in[1];
    const float* tau       = (const float*)d_in[2];
    const float* v         = (const float*)d_in[3];
    float* out = (float*)d_out;
    unsigned long long* masks = (unsigned long long*)d_ws;  // B*T*16 u64 = 4.19 MB

    dim3 g1(TT / L1SEG, DD / DT, BB);   // 16 x 4 x 8 = 512 blocks
    lif_spike_kernel<<<g1, 256, 0, stream>>>(x, threshold, tau, v, masks);

    dim3 g2(TT / TC, BB);               // 256 x 8 = 2048 blocks
    lif_norm_kernel<<<g2, 256, 0, stream>>>(masks, out);
}

// Round 7
// 247.621 us; speedup vs baseline: 1.0225x; 1.0225x over previous
//
#include <hip/hip_runtime.h>

#define BB 8
#define TT 4096
#define DD 1024
#define KK 64
#define DT 256        // channels per K1 block (1 thread = 1 channel)
#define CH 16         // rows per staged chunk
#define L1SEG 256     // output rows per K1 block
#define NCH (KK / CH + L1SEG / CH)   // 4 warm-up + 16 compute chunks = 20
#define NSLOT 5       // LDS ring slots (80 KB -> 2 blocks/CU)  [R3-proven]
#define TC 16         // t-rows per K2 block

// Kernel 1: R3's proven LDS-ring (5 slots, 2 barriers/iter) + depth-2 register
// prefetch. Chunk k covers rows [t0-64 + k*CH, +CH); history row t-64 of chunk
// k is chunk k-4. Per iteration k:
//   loadChunk(k+2) -> rgB               (2 iters of latency cover)
//   compute chunk k (slots k%5, (k-4)%5)
//   barrier
//   writeChunk(k+1) from rgA -> slot (k+1)%5 == (k-4)%5  (chunk k-4, dead)
//   barrier;  rgA = rgB
// Identical slot liveness to R3; only load-issue timing changed (regs private).
__global__ __launch_bounds__(256) void lif_spike_kernel(
    const float* __restrict__ x, const float* __restrict__ threshold,
    const float* __restrict__ tau, const float* __restrict__ v0p,
    unsigned long long* __restrict__ masks)
{
    __shared__ float ring[NSLOT][CH][DT];   // 5*16*256*4 = 80 KB
    const int tid   = threadIdx.x;
    const int tseg  = blockIdx.x;
    const int dtile = blockIdx.y;
    const int b     = blockIdx.z;
    const int d     = dtile * DT + tid;
    const int t0    = tseg * L1SEG;

    double tc = (double)tau[d];
    tc = tc < 0.001 ? 0.001 : (tc > 0.999 ? 0.999 : tc);
    const double ltau = log(tc);
    const double c64  = exp(64.0 * ltau);   // tau^64
    const double thr  = (double)threshold[d];
    const double v0   = (double)v0p[d];
    double pw  = exp((double)(t0 + 1) * ltau);
    double acc = 0.0;

    const float* xb = x + ((size_t)b * TT) * DD + dtile * DT;
    const int lane = tid & 63;
    const int wg   = dtile * 4 + (tid >> 6);
    unsigned long long* mrow = masks + ((size_t)b * TT) * 16 + wg;

    float4 rgA[4], rgB[4];

    auto loadChunk = [&](int k, float4* rg) {
        const int rstart = t0 - KK + k * CH;
        #pragma unroll
        for (int l = 0; l < 4; ++l) {
            const int f   = l * 256 + tid;   // float4 index within 16x256 chunk
            const int row = f >> 6;          // 64 float4 per row
            const int c4  = f & 63;
            const int rr  = rstart + row;
            if (rr >= 0)
                rg[l] = *(const float4*)(xb + (size_t)rr * DD + c4 * 4);
            else
                rg[l] = make_float4(0.f, 0.f, 0.f, 0.f);
        }
    };
    auto writeChunk = [&](int k, const float4* rg) {
        const int s = k % NSLOT;
        #pragma unroll
        for (int l = 0; l < 4; ++l) {
            const int f   = l * 256 + tid;
            const int row = f >> 6;
            const int c4  = f & 63;
            *(float4*)&ring[s][row][c4 * 4] = rg[l];
        }
    };

    // Prologue: stage chunks 0..4 into slots 0..4; preload chunk 5 -> rgA.
    #pragma unroll
    for (int k = 0; k < NSLOT; ++k) { loadChunk(k, rgA); writeChunk(k, rgA); }
    loadChunk(NSLOT, rgA);
    __syncthreads();

    // Warm-up: 64 rows (chunks 0..3) build the running window sum
    #pragma unroll
    for (int k = 0; k < KK / CH; ++k) {
        #pragma unroll
        for (int i = 0; i < CH; ++i)
            acc = fma(tc, acc, (double)ring[k][i][tid]);
    }

    // Main loop: compute chunk k; stage k+1 (regs->LDS); prefetch k+2 (glb->regs)
    for (int k = KK / CH; k < NCH; ++k) {
        if (k + 2 < NCH) loadChunk(k + 2, rgB);
        const int cs = k % NSLOT, hs = (k - 4) % NSLOT;
        const int tbase = t0 + (k - KK / CH) * CH;
        #pragma unroll
        for (int i = 0; i < CH; ++i) {
            const float xv = ring[cs][i][tid];
            const float ov = ring[hs][i][tid];
            acc = fma(tc, acc, (double)xv);      // + x[t]
            acc = fma(-c64, (double)ov, acc);    // - tau^64 * x[t-64]
            const double vint = fma(v0, pw, acc);
            pw *= tc;
            const unsigned long long m = __ballot(vint >= thr);
            if (lane == 0) mrow[(size_t)(tbase + i) * 16] = m;
        }
        __syncthreads();
        if (k + 1 < NCH) writeChunk(k + 1, rgA);
        __syncthreads();
        #pragma unroll
        for (int l = 0; l < 4; ++l) rgA[l] = rgB[l];
    }
}

// Kernel 2: popcount -> denom -> normalized float4 output (unchanged control)
__global__ __launch_bounds__(256) void lif_norm_kernel(
    const unsigned long long* __restrict__ masks,
    float* __restrict__ out)
{
    __shared__ unsigned long long mw[TC * 16];
    __shared__ float rcp[TC];
    const int tid    = threadIdx.x;
    const int tchunk = blockIdx.x;
    const int b      = blockIdx.y;
    const int tbase  = tchunk * TC;

    mw[tid] = masks[((size_t)b * TT + tbase) * 16 + tid];
    __syncthreads();

    if (tid < TC) {
        int cnt = 0;
        #pragma unroll
        for (int w = 0; w < 16; ++w) cnt += __popcll(mw[tid * 16 + w]);
        rcp[tid] = 1.0f / fmaxf((float)cnt, 1.0f);
    }
    __syncthreads();

    float4* outb = (float4*)(out + ((size_t)b * TT + tbase) * DD) + tid;
    #pragma unroll
    for (int t = 0; t < TC; ++t) {
        const unsigned long long w = mw[t * 16 + (tid >> 4)];
        const unsigned int bits = (unsigned int)(w >> ((tid & 15) * 4)) & 0xFu;
        const float r = rcp[t];
        float4 o;
        o.x = (bits & 1u) ? r : 0.0f;
        o.y = (bits & 2u) ? r : 0.0f;
        o.z = (bits & 4u) ? r : 0.0f;
        o.w = (bits & 8u) ? r : 0.0f;
        outb[t * (DD / 4)] = o;
    }
}

extern "C" void kernel_launch(void* const* d_in, const int* in_sizes, int n_in,
                              void* d_out, int out_size, void* d_ws, size_t ws_size,
                              hipStream_t stream) {
    const float* x         = (const float*)d_in[0];
    const float* threshold = (const float*)d_in[1];
    const float* tau       = (const float*)d_in[2];
    const float* v         = (const float*)d_in[3];
    float* out = (float*)d_out;
    unsigned long long* masks = (unsigned long long*)d_ws;  // B*T*16 u64 = 4.19 MB

    dim3 g1(TT / L1SEG, DD / DT, BB);   // 16 x 4 x 8 = 512 blocks
    lif_spike_kernel<<<g1, 256, 0, stream>>>(x, threshold, tau, v, masks);

    dim3 g2(TT / TC, BB);               // 256 x 8 = 2048 blocks
    lif_norm_kernel<<<g2, 256, 0, stream>>>(masks, out);
}